// Round 5
// baseline (140.839 us; speedup 1.0000x reference)
//
#include <hip/hip_runtime.h>
#include <hip/hip_bf16.h>

#define T_TOK 256
#define C_DIM 1024
#define H_DIM 2048
#define E_NUM 8

typedef __attribute__((ext_vector_type(4))) float f32x4;
typedef __attribute__((ext_vector_type(8))) short short8;

// workspace layout (bytes)
#define WS_CNT    0
#define WS_LIST   1024
#define WS_XBF    16384                      // 256*1024*2 = 512 KB
#define WS_HBUF   (1u<<20)                   // 1 MB bf16
#define WS_HSBUF  (2u<<20)                   // 1 MB bf16
#define WS_UPART  (3u<<20)                   // 2*256*2048*4 = 4 MB
#define WS_GPART  (7u<<20)                   // 4 MB
#define WS_USPART (11u<<20)                  // 4 MB
#define WS_GSPART (15u<<20)                  // 4 MB
#define WS_YPART  (19u<<20)                  // 2*256*1024*4 = 2 MB
#define WS_YSPART (21u<<20)                  // 2 MB  (end 23 MB)

#define THS ((size_t)T_TOK * H_DIM)
#define TCS ((size_t)T_TOK * C_DIM)

__device__ __forceinline__ ushort f2bf(float f) {
    __hip_bfloat16 h = __float2bfloat16(f);
    return *reinterpret_cast<ushort*>(&h);
}

__device__ __forceinline__ short8 pack8(float4 a, float4 b) {
    short8 s;
    s[0] = (short)f2bf(a.x); s[1] = (short)f2bf(a.y);
    s[2] = (short)f2bf(a.z); s[3] = (short)f2bf(a.w);
    s[4] = (short)f2bf(b.x); s[5] = (short)f2bf(b.y);
    s[6] = (short)f2bf(b.z); s[7] = (short)f2bf(b.w);
    return s;
}

#define MFMA(a, b, c) __builtin_amdgcn_mfma_f32_16x16x32_bf16((a), (b), (c), 0, 0, 0)

__global__ __launch_bounds__(256) void prep_kernel(const float* __restrict__ x,
                                                   ushort* __restrict__ xbf)
{
    int i = blockIdx.x * 256 + threadIdx.x;   // 32768 threads, 8 elems each
    float4 a = reinterpret_cast<const float4*>(x)[i * 2];
    float4 b = reinterpret_cast<const float4*>(x)[i * 2 + 1];
    *reinterpret_cast<short8*>(xbf + (size_t)i * 8) = pack8(a, b);
}

__global__ __launch_bounds__(256) void router_kernel(
    const float* __restrict__ x, const float* __restrict__ router,
    int* __restrict__ cnt, int* __restrict__ list)
{
    const int t = blockIdx.x;
    const int tid = threadIdx.x;
    float4 xv = reinterpret_cast<const float4*>(x + (size_t)t * C_DIM)[tid];
    float p[E_NUM];
#pragma unroll
    for (int e = 0; e < E_NUM; e++) {
        float4 rv = reinterpret_cast<const float4*>(router + (size_t)e * C_DIM)[tid];
        p[e] = xv.x * rv.x + xv.y * rv.y + xv.z * rv.z + xv.w * rv.w;
    }
#pragma unroll
    for (int e = 0; e < E_NUM; e++) {
#pragma unroll
        for (int off = 32; off >= 1; off >>= 1)
            p[e] += __shfl_down(p[e], off, 64);
    }
    __shared__ float red[E_NUM][4];
    const int lane = tid & 63, wv = tid >> 6;
    if (lane == 0) {
#pragma unroll
        for (int e = 0; e < E_NUM; e++) red[e][wv] = p[e];
    }
    __syncthreads();
    if (tid == 0) {
        float best = -3.4e38f; int bi = 0;
#pragma unroll
        for (int e = 0; e < E_NUM; e++) {
            float v = red[e][0] + red[e][1] + red[e][2] + red[e][3];
            if (v > best) { best = v; bi = e; }
        }
        int pos = atomicAdd(&cnt[bi], 1);
        list[bi * T_TOK + pos] = t;
    }
}

// up/gate GEMM, barrier-free streaming, split-K partials.
// grid (9, H/64=32, 16). experts: BM=32 (tt=z>>1, kz=z&1, chunk 512).
// shared (e==8): BM=64 (z<8: tt=z>>1 of 4, kz=z&1, chunk 512).
__global__ __launch_bounds__(256, 2) void ug_mfma(
    const ushort* __restrict__ xbf, const float* __restrict__ up, const float* __restrict__ gate,
    const float* __restrict__ w_up_s, const float* __restrict__ w_gate_s,
    const int* __restrict__ cnt, const int* __restrict__ list,
    float* __restrict__ upart, float* __restrict__ gpart,
    float* __restrict__ uspart, float* __restrict__ gspart)
{
    const int e = blockIdx.x, by = blockIdx.y, z = blockIdx.z;
    const int tid = threadIdx.x, lane = tid & 63, wv = tid >> 6;
    const int col = lane & 15, kg = lane >> 4, kl = kg * 8;
    const int hglob = by * 64 + wv * 16 + col;

    if (e < E_NUM) {
        const int n = cnt[e];
        const int tt = z >> 1, kz = z & 1;
        if (tt * 32 >= n) return;
        __shared__ int toks_s[32];
        if (tid < 32) {
            int t = tt * 32 + tid;
            toks_s[tid] = (t < n) ? list[e * T_TOK + t] : -1;
        }
        __syncthreads();
        const int kc0 = kz * 512;
        const float* pu = up   + ((size_t)e * H_DIM + hglob) * C_DIM + kc0 + kl;
        const float* pg = gate + ((size_t)e * H_DIM + hglob) * C_DIM + kc0 + kl;
        const int t0 = toks_s[col], t1 = toks_s[16 + col];
        const ushort* pa0 = xbf + (size_t)(t0 < 0 ? 0 : t0) * C_DIM + kc0 + kl;
        const ushort* pa1 = xbf + (size_t)(t1 < 0 ? 0 : t1) * C_DIM + kc0 + kl;
        f32x4 au0 = {0,0,0,0}, au1 = {0,0,0,0}, ag0 = {0,0,0,0}, ag1 = {0,0,0,0};
#pragma unroll 4
        for (int k = 0; k < 16; k += 2) {
            const int o0 = k * 32, o1 = o0 + 32;
            short8 a00 = *reinterpret_cast<const short8*>(pa0 + o0);
            short8 a10 = *reinterpret_cast<const short8*>(pa1 + o0);
            short8 a01 = *reinterpret_cast<const short8*>(pa0 + o1);
            short8 a11 = *reinterpret_cast<const short8*>(pa1 + o1);
            float4 ua0 = *reinterpret_cast<const float4*>(pu + o0);
            float4 ub0 = *reinterpret_cast<const float4*>(pu + o0 + 4);
            float4 ua1 = *reinterpret_cast<const float4*>(pu + o1);
            float4 ub1 = *reinterpret_cast<const float4*>(pu + o1 + 4);
            float4 ga0 = *reinterpret_cast<const float4*>(pg + o0);
            float4 gb0 = *reinterpret_cast<const float4*>(pg + o0 + 4);
            float4 ga1 = *reinterpret_cast<const float4*>(pg + o1);
            float4 gb1 = *reinterpret_cast<const float4*>(pg + o1 + 4);
            short8 bu0 = pack8(ua0, ub0), bu1 = pack8(ua1, ub1);
            short8 bg0 = pack8(ga0, gb0), bg1 = pack8(ga1, gb1);
            au0 = MFMA(a00, bu0, au0); au1 = MFMA(a10, bu0, au1);
            ag0 = MFMA(a00, bg0, ag0); ag1 = MFMA(a10, bg0, ag1);
            au0 = MFMA(a01, bu1, au0); au1 = MFMA(a11, bu1, au1);
            ag0 = MFMA(a01, bg1, ag0); ag1 = MFMA(a11, bg1, ag1);
        }
        float* ub = upart + (size_t)kz * THS;
        float* gb = gpart + (size_t)kz * THS;
#pragma unroll
        for (int r = 0; r < 4; r++) {
            int m = kg * 4 + r;
            int tk0 = toks_s[m];
            if (tk0 >= 0) {
                ub[(size_t)tk0 * H_DIM + hglob] = au0[r];
                gb[(size_t)tk0 * H_DIM + hglob] = ag0[r];
            }
            int tk1 = toks_s[16 + m];
            if (tk1 >= 0) {
                ub[(size_t)tk1 * H_DIM + hglob] = au1[r];
                gb[(size_t)tk1 * H_DIM + hglob] = ag1[r];
            }
        }
    } else {
        if (z >= 8) return;
        const int tt = z >> 1, kz = z & 1;
        const int kc0 = kz * 512;
        const float* pu = w_up_s   + (size_t)hglob * C_DIM + kc0 + kl;
        const float* pg = w_gate_s + (size_t)hglob * C_DIM + kc0 + kl;
        const int r0 = tt * 64 + col;
        const ushort* pa[4];
#pragma unroll
        for (int mf = 0; mf < 4; mf++)
            pa[mf] = xbf + (size_t)(r0 + mf * 16) * C_DIM + kc0 + kl;
        f32x4 au[4] = {{0,0,0,0},{0,0,0,0},{0,0,0,0},{0,0,0,0}};
        f32x4 ag[4] = {{0,0,0,0},{0,0,0,0},{0,0,0,0},{0,0,0,0}};
#pragma unroll 4
        for (int k = 0; k < 16; k++) {
            const int o = k * 32;
            float4 ua = *reinterpret_cast<const float4*>(pu + o);
            float4 ub_ = *reinterpret_cast<const float4*>(pu + o + 4);
            float4 ga = *reinterpret_cast<const float4*>(pg + o);
            float4 gb_ = *reinterpret_cast<const float4*>(pg + o + 4);
            short8 bu = pack8(ua, ub_), bg = pack8(ga, gb_);
#pragma unroll
            for (int mf = 0; mf < 4; mf++) {
                short8 a = *reinterpret_cast<const short8*>(pa[mf] + o);
                au[mf] = MFMA(a, bu, au[mf]);
                ag[mf] = MFMA(a, bg, ag[mf]);
            }
        }
        float* ub = uspart + (size_t)kz * THS;
        float* gb = gspart + (size_t)kz * THS;
#pragma unroll
        for (int mf = 0; mf < 4; mf++) {
#pragma unroll
            for (int r = 0; r < 4; r++) {
                int tok = tt * 64 + mf * 16 + kg * 4 + r;
                ub[(size_t)tok * H_DIM + hglob] = au[mf][r];
                gb[(size_t)tok * H_DIM + hglob] = ag[mf][r];
            }
        }
    }
}

// h = silu(sum g) * (sum u); writes bf16 hbuf (expert) and hsbuf (shared)
__global__ __launch_bounds__(256) void silu_reduce(
    const float* __restrict__ upart, const float* __restrict__ gpart,
    const float* __restrict__ uspart, const float* __restrict__ gspart,
    ushort* __restrict__ hbuf, ushort* __restrict__ hsbuf)
{
    size_t gid = (size_t)blockIdx.x * 256 + threadIdx.x;   // 131072 threads
    size_t o = gid * 4;
    float4 u = *reinterpret_cast<const float4*>(upart + o);
    float4 u2 = *reinterpret_cast<const float4*>(upart + THS + o);
    float4 g = *reinterpret_cast<const float4*>(gpart + o);
    float4 g2 = *reinterpret_cast<const float4*>(gpart + THS + o);
    u.x += u2.x; u.y += u2.y; u.z += u2.z; u.w += u2.w;
    g.x += g2.x; g.y += g2.y; g.z += g2.z; g.w += g2.w;
    ushort4 hw;
    hw.x = f2bf(u.x * (g.x / (1.f + __expf(-g.x))));
    hw.y = f2bf(u.y * (g.y / (1.f + __expf(-g.y))));
    hw.z = f2bf(u.z * (g.z / (1.f + __expf(-g.z))));
    hw.w = f2bf(u.w * (g.w / (1.f + __expf(-g.w))));
    *reinterpret_cast<ushort4*>(hbuf + o) = hw;

    float4 us = *reinterpret_cast<const float4*>(uspart + o);
    float4 us2 = *reinterpret_cast<const float4*>(uspart + THS + o);
    float4 gs = *reinterpret_cast<const float4*>(gspart + o);
    float4 gs2 = *reinterpret_cast<const float4*>(gspart + THS + o);
    us.x += us2.x; us.y += us2.y; us.z += us2.z; us.w += us2.w;
    gs.x += gs2.x; gs.y += gs2.y; gs.z += gs2.z; gs.w += gs2.w;
    ushort4 hsw;
    hsw.x = f2bf(us.x * (gs.x / (1.f + __expf(-gs.x))));
    hsw.y = f2bf(us.y * (gs.y / (1.f + __expf(-gs.y))));
    hsw.z = f2bf(us.z * (gs.z / (1.f + __expf(-gs.z))));
    hsw.w = f2bf(us.w * (gs.w / (1.f + __expf(-gs.w))));
    *reinterpret_cast<ushort4*>(hsbuf + o) = hsw;
}

// down GEMM. grid (9, C/64=16, 16). experts: BM=32, kz chunk 1024.
// shared: BM=64 (z<8), kz chunk 1024.
__global__ __launch_bounds__(256, 2) void down_mfma(
    const float* __restrict__ dwn, const float* __restrict__ w_down_s,
    const ushort* __restrict__ hbuf, const ushort* __restrict__ hsbuf,
    const int* __restrict__ cnt, const int* __restrict__ list,
    float* __restrict__ ypart, float* __restrict__ yspart)
{
    const int e = blockIdx.x, by = blockIdx.y, z = blockIdx.z;
    const int tid = threadIdx.x, lane = tid & 63, wv = tid >> 6;
    const int col = lane & 15, kg = lane >> 4, kl = kg * 8;
    const int cglob = by * 64 + wv * 16 + col;

    if (e < E_NUM) {
        const int n = cnt[e];
        const int tt = z >> 1, kz = z & 1;
        if (tt * 32 >= n) return;
        __shared__ int toks_s[32];
        if (tid < 32) {
            int t = tt * 32 + tid;
            toks_s[tid] = (t < n) ? list[e * T_TOK + t] : -1;
        }
        __syncthreads();
        const int kc0 = kz * 1024;
        const float* pd = dwn + ((size_t)e * C_DIM + cglob) * H_DIM + kc0 + kl;
        const int t0 = toks_s[col], t1 = toks_s[16 + col];
        const ushort* pa0 = hbuf + (size_t)(t0 < 0 ? 0 : t0) * H_DIM + kc0 + kl;
        const ushort* pa1 = hbuf + (size_t)(t1 < 0 ? 0 : t1) * H_DIM + kc0 + kl;
        f32x4 ac0 = {0,0,0,0}, ac1 = {0,0,0,0};
#pragma unroll 4
        for (int k = 0; k < 32; k += 2) {
            const int o0 = k * 32, o1 = o0 + 32;
            short8 a00 = *reinterpret_cast<const short8*>(pa0 + o0);
            short8 a10 = *reinterpret_cast<const short8*>(pa1 + o0);
            short8 a01 = *reinterpret_cast<const short8*>(pa0 + o1);
            short8 a11 = *reinterpret_cast<const short8*>(pa1 + o1);
            float4 da0 = *reinterpret_cast<const float4*>(pd + o0);
            float4 db0 = *reinterpret_cast<const float4*>(pd + o0 + 4);
            float4 da1 = *reinterpret_cast<const float4*>(pd + o1);
            float4 db1 = *reinterpret_cast<const float4*>(pd + o1 + 4);
            short8 bd0 = pack8(da0, db0), bd1 = pack8(da1, db1);
            ac0 = MFMA(a00, bd0, ac0); ac1 = MFMA(a10, bd0, ac1);
            ac0 = MFMA(a01, bd1, ac0); ac1 = MFMA(a11, bd1, ac1);
        }
        float* yb = ypart + (size_t)kz * TCS;
#pragma unroll
        for (int r = 0; r < 4; r++) {
            int m = kg * 4 + r;
            int tk0 = toks_s[m];
            if (tk0 >= 0) yb[(size_t)tk0 * C_DIM + cglob] = ac0[r];
            int tk1 = toks_s[16 + m];
            if (tk1 >= 0) yb[(size_t)tk1 * C_DIM + cglob] = ac1[r];
        }
    } else {
        if (z >= 8) return;
        const int tt = z >> 1, kz = z & 1;
        const int kc0 = kz * 1024;
        const float* pd = w_down_s + (size_t)cglob * H_DIM + kc0 + kl;
        const int r0 = tt * 64 + col;
        const ushort* pa[4];
#pragma unroll
        for (int mf = 0; mf < 4; mf++)
            pa[mf] = hsbuf + (size_t)(r0 + mf * 16) * H_DIM + kc0 + kl;
        f32x4 ac[4] = {{0,0,0,0},{0,0,0,0},{0,0,0,0},{0,0,0,0}};
#pragma unroll 4
        for (int k = 0; k < 32; k++) {
            const int o = k * 32;
            float4 da = *reinterpret_cast<const float4*>(pd + o);
            float4 db = *reinterpret_cast<const float4*>(pd + o + 4);
            short8 bd = pack8(da, db);
#pragma unroll
            for (int mf = 0; mf < 4; mf++) {
                short8 a = *reinterpret_cast<const short8*>(pa[mf] + o);
                ac[mf] = MFMA(a, bd, ac[mf]);
            }
        }
        float* yb = yspart + (size_t)kz * TCS;
#pragma unroll
        for (int mf = 0; mf < 4; mf++) {
#pragma unroll
            for (int r = 0; r < 4; r++) {
                int tok = tt * 64 + mf * 16 + kg * 4 + r;
                yb[(size_t)tok * C_DIM + cglob] = ac[mf][r];
            }
        }
    }
}

__global__ __launch_bounds__(256) void yreduce(
    const float* __restrict__ ypart, const float* __restrict__ yspart,
    float* __restrict__ y)
{
    size_t gid = (size_t)blockIdx.x * 256 + threadIdx.x;   // 65536 threads
    size_t o = gid * 4;
    float4 a = *reinterpret_cast<const float4*>(ypart + o);
    float4 b = *reinterpret_cast<const float4*>(ypart + TCS + o);
    float4 c = *reinterpret_cast<const float4*>(yspart + o);
    float4 d = *reinterpret_cast<const float4*>(yspart + TCS + o);
    float4 r;
    r.x = a.x + b.x + c.x + d.x;
    r.y = a.y + b.y + c.y + d.y;
    r.z = a.z + b.z + c.z + d.z;
    r.w = a.w + b.w + c.w + d.w;
    *reinterpret_cast<float4*>(y + o) = r;
}

extern "C" void kernel_launch(void* const* d_in, const int* in_sizes, int n_in,
                              void* d_out, int out_size, void* d_ws, size_t ws_size,
                              hipStream_t stream)
{
    const float* x        = (const float*)d_in[0];
    const float* up       = (const float*)d_in[1];
    const float* gate     = (const float*)d_in[2];
    const float* dwn      = (const float*)d_in[3];
    const float* router   = (const float*)d_in[4];
    const float* w_up_s   = (const float*)d_in[5];
    const float* w_gate_s = (const float*)d_in[6];
    const float* w_down_s = (const float*)d_in[7];

    char* ws = (char*)d_ws;
    int* cnt      = (int*)(ws + WS_CNT);
    int* list     = (int*)(ws + WS_LIST);
    ushort* xbf   = (ushort*)(ws + WS_XBF);
    ushort* hbuf  = (ushort*)(ws + WS_HBUF);
    ushort* hsbuf = (ushort*)(ws + WS_HSBUF);
    float* upart  = (float*)(ws + WS_UPART);
    float* gpart  = (float*)(ws + WS_GPART);
    float* uspart = (float*)(ws + WS_USPART);
    float* gspart = (float*)(ws + WS_GSPART);
    float* ypart  = (float*)(ws + WS_YPART);
    float* yspart = (float*)(ws + WS_YSPART);
    float* y = (float*)d_out;

    hipMemsetAsync(cnt, 0, E_NUM * sizeof(int), stream);
    prep_kernel<<<128, 256, 0, stream>>>(x, xbf);
    router_kernel<<<T_TOK, 256, 0, stream>>>(x, router, cnt, list);
    ug_mfma<<<dim3(E_NUM + 1, H_DIM / 64, 16), 256, 0, stream>>>(
        xbf, up, gate, w_up_s, w_gate_s, cnt, list, upart, gpart, uspart, gspart);
    silu_reduce<<<512, 256, 0, stream>>>(upart, gpart, uspart, gspart, hbuf, hsbuf);
    down_mfma<<<dim3(E_NUM + 1, C_DIM / 64, 16), 256, 0, stream>>>(
        dwn, w_down_s, hbuf, hsbuf, cnt, list, ypart, yspart);
    yreduce<<<256, 256, 0, stream>>>(ypart, yspart, y);
}

// Round 6
// 114.466 us; speedup vs baseline: 1.2304x; 1.2304x over previous
//
#include <hip/hip_runtime.h>
#include <hip/hip_bf16.h>

#define T_TOK 256
#define C_DIM 1024
#define H_DIM 2048
#define E_NUM 8

typedef __attribute__((ext_vector_type(4))) float f32x4;
typedef __attribute__((ext_vector_type(8))) short short8;

// workspace layout (bytes)
#define WS_CNT    0
#define WS_LIST   1024
#define WS_XBF    16384                      // 256*1024*2 = 512 KB
#define WS_HBUF   (1u<<20)                   // 1 MB bf16 (expert h)
#define WS_HSBUF  (2u<<20)                   // 1 MB bf16 (shared h)
#define WS_YS     (3u<<20)                   // 1 MB f32 (shared y)

__device__ __forceinline__ ushort f2bf(float f) {
    __hip_bfloat16 h = __float2bfloat16(f);
    return *reinterpret_cast<ushort*>(&h);
}

__device__ __forceinline__ short8 pack8(float4 a, float4 b) {
    short8 s;
    s[0] = (short)f2bf(a.x); s[1] = (short)f2bf(a.y);
    s[2] = (short)f2bf(a.z); s[3] = (short)f2bf(a.w);
    s[4] = (short)f2bf(b.x); s[5] = (short)f2bf(b.y);
    s[6] = (short)f2bf(b.z); s[7] = (short)f2bf(b.w);
    return s;
}

#define MFMA(a, b, c) __builtin_amdgcn_mfma_f32_16x16x32_bf16((a), (b), (c), 0, 0, 0)

// router + x->bf16 prep fused. 1 block per token.
__global__ __launch_bounds__(256) void router_kernel(
    const float* __restrict__ x, const float* __restrict__ router,
    int* __restrict__ cnt, int* __restrict__ list, ushort* __restrict__ xbf)
{
    const int t = blockIdx.x;
    const int tid = threadIdx.x;
    float4 xv = reinterpret_cast<const float4*>(x + (size_t)t * C_DIM)[tid];
    // emit bf16 x
    ushort4 xb;
    xb.x = f2bf(xv.x); xb.y = f2bf(xv.y); xb.z = f2bf(xv.z); xb.w = f2bf(xv.w);
    *reinterpret_cast<ushort4*>(xbf + (size_t)t * C_DIM + tid * 4) = xb;

    float p[E_NUM];
#pragma unroll
    for (int e = 0; e < E_NUM; e++) {
        float4 rv = reinterpret_cast<const float4*>(router + (size_t)e * C_DIM)[tid];
        p[e] = xv.x * rv.x + xv.y * rv.y + xv.z * rv.z + xv.w * rv.w;
    }
#pragma unroll
    for (int e = 0; e < E_NUM; e++) {
#pragma unroll
        for (int off = 32; off >= 1; off >>= 1)
            p[e] += __shfl_down(p[e], off, 64);
    }
    __shared__ float red[E_NUM][4];
    const int lane = tid & 63, wv = tid >> 6;
    if (lane == 0) {
#pragma unroll
        for (int e = 0; e < E_NUM; e++) red[e][wv] = p[e];
    }
    __syncthreads();
    if (tid == 0) {
        float best = -3.4e38f; int bi = 0;
#pragma unroll
        for (int e = 0; e < E_NUM; e++) {
            float v = red[e][0] + red[e][1] + red[e][2] + red[e][3];
            if (v > best) { best = v; bi = e; }
        }
        int pos = atomicAdd(&cnt[bi], 1);
        list[bi * T_TOK + pos] = t;
    }
}

// up/gate GEMM: BM=32, BN=16, in-block split-K (wave w -> k in [w*256,(w+1)*256)).
// grid (9 [8=shared], H/16=128, 8 token-tiles), block 256. Barrier-free K-loop.
__global__ __launch_bounds__(256, 4) void ug_mfma(
    const ushort* __restrict__ xbf, const float* __restrict__ up, const float* __restrict__ gate,
    const float* __restrict__ w_up_s, const float* __restrict__ w_gate_s,
    const int* __restrict__ cnt, const int* __restrict__ list,
    ushort* __restrict__ hbuf, ushort* __restrict__ hsbuf)
{
    const int e = blockIdx.x, by = blockIdx.y, tt = blockIdx.z;
    const bool sh = (e == E_NUM);
    const int n = sh ? T_TOK : cnt[e];
    if (tt * 32 >= n) return;
    const int tid = threadIdx.x, lane = tid & 63, wv = tid >> 6;
    const int col = lane & 15, kg = lane >> 4, kl = kg * 8;

    __shared__ float red[4][2][64][4];
    __shared__ int toks_s[32];
    if (tid < 32) {
        int t = tt * 32 + tid;
        toks_s[tid] = (t < n) ? (sh ? t : list[e * T_TOK + t]) : -1;
    }
    __syncthreads();

    const int h0 = by * 16;
    const int kb = wv * 256;
    const float* __restrict__ pu = (sh ? w_up_s   : up   + (size_t)e * H_DIM * C_DIM)
                                   + (size_t)(h0 + col) * C_DIM + kb + kl;
    const float* __restrict__ pg = (sh ? w_gate_s : gate + (size_t)e * H_DIM * C_DIM)
                                   + (size_t)(h0 + col) * C_DIM + kb + kl;
    const int t0 = toks_s[col], t1 = toks_s[16 + col];
    const ushort* __restrict__ pa0 = xbf + (size_t)(t0 < 0 ? 0 : t0) * C_DIM + kb + kl;
    const ushort* __restrict__ pa1 = xbf + (size_t)(t1 < 0 ? 0 : t1) * C_DIM + kb + kl;

    f32x4 au0 = {0,0,0,0}, au1 = {0,0,0,0}, ag0 = {0,0,0,0}, ag1 = {0,0,0,0};
#pragma unroll 4
    for (int k = 0; k < 8; k++) {
        const int o = k * 32;
        short8 a0 = *reinterpret_cast<const short8*>(pa0 + o);
        short8 a1 = *reinterpret_cast<const short8*>(pa1 + o);
        float4 ua = *reinterpret_cast<const float4*>(pu + o);
        float4 ub = *reinterpret_cast<const float4*>(pu + o + 4);
        float4 ga = *reinterpret_cast<const float4*>(pg + o);
        float4 gb = *reinterpret_cast<const float4*>(pg + o + 4);
        short8 bu = pack8(ua, ub), bg = pack8(ga, gb);
        au0 = MFMA(a0, bu, au0); au1 = MFMA(a1, bu, au1);
        ag0 = MFMA(a0, bg, ag0); ag1 = MFMA(a1, bg, ag1);
    }

    // cross-wave K reduction: round 1 (u), round 2 (g), then silu+emit.
    *reinterpret_cast<f32x4*>(red[wv][0][lane]) = au0;
    *reinterpret_cast<f32x4*>(red[wv][1][lane]) = au1;
    __syncthreads();
    f32x4 u4 = {0,0,0,0}, g4 = {0,0,0,0};
    const int rv = (tid >> 6) & 1, rl = tid & 63;
    if (tid < 128) {
        u4 = *reinterpret_cast<const f32x4*>(red[0][rv][rl]);
        u4 += *reinterpret_cast<const f32x4*>(red[1][rv][rl]);
        u4 += *reinterpret_cast<const f32x4*>(red[2][rv][rl]);
        u4 += *reinterpret_cast<const f32x4*>(red[3][rv][rl]);
    }
    __syncthreads();
    *reinterpret_cast<f32x4*>(red[wv][0][lane]) = ag0;
    *reinterpret_cast<f32x4*>(red[wv][1][lane]) = ag1;
    __syncthreads();
    if (tid < 128) {
        g4 = *reinterpret_cast<const f32x4*>(red[0][rv][rl]);
        g4 += *reinterpret_cast<const f32x4*>(red[1][rv][rl]);
        g4 += *reinterpret_cast<const f32x4*>(red[2][rv][rl]);
        g4 += *reinterpret_cast<const f32x4*>(red[3][rv][rl]);
        ushort* __restrict__ outp = sh ? hsbuf : hbuf;
#pragma unroll
        for (int j = 0; j < 4; j++) {
            int row = (rv ? 16 : 0) + (rl >> 4) * 4 + j;
            int tok = toks_s[row];
            if (tok >= 0) {
                float g = g4[j], u = u4[j];
                float hv = u * (g / (1.f + __expf(-g)));
                outp[(size_t)tok * H_DIM + h0 + (rl & 15)] = f2bf(hv);
            }
        }
    }
}

// down GEMM: BM=32, BN=16, in-block split-K (wave w -> k in [w*512,(w+1)*512)).
// grid (9 [8=shared], C/16=64, 8 token-tiles), block 256.
__global__ __launch_bounds__(256, 4) void down_mfma(
    const float* __restrict__ dwn, const float* __restrict__ w_down_s,
    const ushort* __restrict__ hbuf, const ushort* __restrict__ hsbuf,
    const int* __restrict__ cnt, const int* __restrict__ list,
    float* __restrict__ y, float* __restrict__ yspart)
{
    const int e = blockIdx.x, by = blockIdx.y, tt = blockIdx.z;
    const bool sh = (e == E_NUM);
    const int n = sh ? T_TOK : cnt[e];
    if (tt * 32 >= n) return;
    const int tid = threadIdx.x, lane = tid & 63, wv = tid >> 6;
    const int col = lane & 15, kg = lane >> 4, kl = kg * 8;

    __shared__ float red[4][2][64][4];
    __shared__ int toks_s[32];
    if (tid < 32) {
        int t = tt * 32 + tid;
        toks_s[tid] = (t < n) ? (sh ? t : list[e * T_TOK + t]) : -1;
    }
    __syncthreads();

    const int c0 = by * 16;
    const int kb = wv * 512;
    const float* __restrict__ pd = (sh ? w_down_s : dwn + (size_t)e * C_DIM * H_DIM)
                                   + (size_t)(c0 + col) * H_DIM + kb + kl;
    const int t0 = toks_s[col], t1 = toks_s[16 + col];
    const ushort* __restrict__ hin = sh ? hsbuf : hbuf;
    const ushort* __restrict__ pa0 = hin + (size_t)(t0 < 0 ? 0 : t0) * H_DIM + kb + kl;
    const ushort* __restrict__ pa1 = hin + (size_t)(t1 < 0 ? 0 : t1) * H_DIM + kb + kl;

    f32x4 ac0 = {0,0,0,0}, ac1 = {0,0,0,0};
#pragma unroll 4
    for (int k = 0; k < 16; k++) {
        const int o = k * 32;
        short8 a0 = *reinterpret_cast<const short8*>(pa0 + o);
        short8 a1 = *reinterpret_cast<const short8*>(pa1 + o);
        float4 da = *reinterpret_cast<const float4*>(pd + o);
        float4 db = *reinterpret_cast<const float4*>(pd + o + 4);
        short8 bd = pack8(da, db);
        ac0 = MFMA(a0, bd, ac0);
        ac1 = MFMA(a1, bd, ac1);
    }

    *reinterpret_cast<f32x4*>(red[wv][0][lane]) = ac0;
    *reinterpret_cast<f32x4*>(red[wv][1][lane]) = ac1;
    __syncthreads();
    const int rv = (tid >> 6) & 1, rl = tid & 63;
    if (tid < 128) {
        f32x4 y4;
        y4  = *reinterpret_cast<const f32x4*>(red[0][rv][rl]);
        y4 += *reinterpret_cast<const f32x4*>(red[1][rv][rl]);
        y4 += *reinterpret_cast<const f32x4*>(red[2][rv][rl]);
        y4 += *reinterpret_cast<const f32x4*>(red[3][rv][rl]);
        float* __restrict__ outp = sh ? yspart : y;
#pragma unroll
        for (int j = 0; j < 4; j++) {
            int row = (rv ? 16 : 0) + (rl >> 4) * 4 + j;
            int tok = toks_s[row];
            if (tok >= 0) outp[(size_t)tok * C_DIM + c0 + (rl & 15)] = y4[j];
        }
    }
}

__global__ __launch_bounds__(256) void add_kernel(float* __restrict__ y, const float* __restrict__ ys)
{
    int i = blockIdx.x * 256 + threadIdx.x;
    float4 a = reinterpret_cast<float4*>(y)[i];
    float4 b = reinterpret_cast<const float4*>(ys)[i];
    a.x += b.x; a.y += b.y; a.z += b.z; a.w += b.w;
    reinterpret_cast<float4*>(y)[i] = a;
}

extern "C" void kernel_launch(void* const* d_in, const int* in_sizes, int n_in,
                              void* d_out, int out_size, void* d_ws, size_t ws_size,
                              hipStream_t stream)
{
    const float* x        = (const float*)d_in[0];
    const float* up       = (const float*)d_in[1];
    const float* gate     = (const float*)d_in[2];
    const float* dwn      = (const float*)d_in[3];
    const float* router   = (const float*)d_in[4];
    const float* w_up_s   = (const float*)d_in[5];
    const float* w_gate_s = (const float*)d_in[6];
    const float* w_down_s = (const float*)d_in[7];

    char* ws = (char*)d_ws;
    int* cnt      = (int*)(ws + WS_CNT);
    int* list     = (int*)(ws + WS_LIST);
    ushort* xbf   = (ushort*)(ws + WS_XBF);
    ushort* hbuf  = (ushort*)(ws + WS_HBUF);
    ushort* hsbuf = (ushort*)(ws + WS_HSBUF);
    float* yspart = (float*)(ws + WS_YS);
    float* y = (float*)d_out;

    hipMemsetAsync(cnt, 0, E_NUM * sizeof(int), stream);
    router_kernel<<<T_TOK, 256, 0, stream>>>(x, router, cnt, list, xbf);
    ug_mfma<<<dim3(E_NUM + 1, H_DIM / 16, 8), 256, 0, stream>>>(
        xbf, up, gate, w_up_s, w_gate_s, cnt, list, hbuf, hsbuf);
    down_mfma<<<dim3(E_NUM + 1, C_DIM / 16, 8), 256, 0, stream>>>(
        dwn, w_down_s, hbuf, hsbuf, cnt, list, y, yspart);
    add_kernel<<<(T_TOK * C_DIM / 4) / 256, 256, 0, stream>>>(y, yspart);
}

// Round 7
// 88.159 us; speedup vs baseline: 1.5975x; 1.2984x over previous
//
#include <hip/hip_runtime.h>
#include <hip/hip_bf16.h>

#define T_TOK 256
#define C_DIM 1024
#define H_DIM 2048
#define E_NUM 8

typedef __attribute__((ext_vector_type(4))) float f32x4;
typedef __attribute__((ext_vector_type(8))) short short8;

// workspace layout (bytes)
#define WS_CNT    0
#define WS_LIST   1024
#define WS_XBF    16384                      // 256*1024*2 = 512 KB
#define WS_HBUF   (1u<<20)                   // 1 MB bf16 (expert h)
#define WS_HSBUF  (2u<<20)                   // 1 MB bf16 (shared h)
#define WS_YS     (3u<<20)                   // 1 MB f32 (shared y)

__device__ __forceinline__ ushort f2bf(float f) {
    __hip_bfloat16 h = __float2bfloat16(f);
    return *reinterpret_cast<ushort*>(&h);
}

__device__ __forceinline__ short8 pack8(float4 a, float4 b) {
    short8 s;
    s[0] = (short)f2bf(a.x); s[1] = (short)f2bf(a.y);
    s[2] = (short)f2bf(a.z); s[3] = (short)f2bf(a.w);
    s[4] = (short)f2bf(b.x); s[5] = (short)f2bf(b.y);
    s[6] = (short)f2bf(b.z); s[7] = (short)f2bf(b.w);
    return s;
}

// async global->LDS DMA, 16B per lane. lds base must be wave-uniform;
// HW writes lds_base + lane*16; global src is per-lane.
__device__ __forceinline__ void gload16(const void* g, void* l) {
    __builtin_amdgcn_global_load_lds((const __attribute__((address_space(1))) void*)g,
                                     (__attribute__((address_space(3))) void*)l, 16, 0, 0);
}

#define MFMA(a, b, c) __builtin_amdgcn_mfma_f32_16x16x32_bf16((a), (b), (c), 0, 0, 0)

// router + x->bf16 prep fused. 1 block per token.
__global__ __launch_bounds__(256) void router_kernel(
    const float* __restrict__ x, const float* __restrict__ router,
    int* __restrict__ cnt, int* __restrict__ list, ushort* __restrict__ xbf)
{
    const int t = blockIdx.x;
    const int tid = threadIdx.x;
    float4 xv = reinterpret_cast<const float4*>(x + (size_t)t * C_DIM)[tid];
    ushort4 xb;
    xb.x = f2bf(xv.x); xb.y = f2bf(xv.y); xb.z = f2bf(xv.z); xb.w = f2bf(xv.w);
    *reinterpret_cast<ushort4*>(xbf + (size_t)t * C_DIM + tid * 4) = xb;

    float p[E_NUM];
#pragma unroll
    for (int e = 0; e < E_NUM; e++) {
        float4 rv = reinterpret_cast<const float4*>(router + (size_t)e * C_DIM)[tid];
        p[e] = xv.x * rv.x + xv.y * rv.y + xv.z * rv.z + xv.w * rv.w;
    }
#pragma unroll
    for (int e = 0; e < E_NUM; e++) {
#pragma unroll
        for (int off = 32; off >= 1; off >>= 1)
            p[e] += __shfl_down(p[e], off, 64);
    }
    __shared__ float red[E_NUM][4];
    const int lane = tid & 63, wv = tid >> 6;
    if (lane == 0) {
#pragma unroll
        for (int e = 0; e < E_NUM; e++) red[e][wv] = p[e];
    }
    __syncthreads();
    if (tid == 0) {
        float best = -3.4e38f; int bi = 0;
#pragma unroll
        for (int e = 0; e < E_NUM; e++) {
            float v = red[e][0] + red[e][1] + red[e][2] + red[e][3];
            if (v > best) { best = v; bi = e; }
        }
        int pos = atomicAdd(&cnt[bi], 1);
        list[bi * T_TOK + pos] = t;
    }
}

// ug: BM=32 tokens x BN=32 h-rows, K=1024 in 16 chunks of 64 f32.
// Weights DMA'd to LDS via global_load_lds (XOR-swizzled source, linear dest),
// x gathered bf16 likewise. 2-barrier double-buffered loop (m97 structure).
// 4 waves = (mf,nf) quadrants. grid (9 [8=shared], H/32=64, 8 token-tiles).
__global__ __launch_bounds__(256) void ug_mfma(
    const ushort* __restrict__ xbf, const float* __restrict__ up, const float* __restrict__ gate,
    const float* __restrict__ w_up_s, const float* __restrict__ w_gate_s,
    const int* __restrict__ cnt, const int* __restrict__ list,
    ushort* __restrict__ hbuf, ushort* __restrict__ hsbuf)
{
    const int e = blockIdx.x, by = blockIdx.y, tt = blockIdx.z;
    const bool sh = (e == E_NUM);
    const int n = sh ? T_TOK : cnt[e];
    if (tt * 32 >= n) return;
    const int tid = threadIdx.x, lane = tid & 63, wv = tid >> 6;

    __shared__ float4 WuS[2][512];   // [32 rows][16 units] per buf, swizzled
    __shared__ float4 WgS[2][512];
    __shared__ ushort XS[2][2048];   // [32 rows][8 units of 8 bf16] per buf
    __shared__ int toks_s[32];
    if (tid < 32) {
        int t = tt * 32 + tid;
        toks_s[tid] = (t < n) ? (sh ? t : list[e * T_TOK + t]) : -1;
    }
    __syncthreads();

    const int n0 = by * 32;
    const float* __restrict__ ub = (sh ? w_up_s   : up   + (size_t)e * H_DIM * C_DIM) + (size_t)n0 * C_DIM;
    const float* __restrict__ gb = (sh ? w_gate_s : gate + (size_t)e * H_DIM * C_DIM) + (size_t)n0 * C_DIM;

    // per-wave staging: slots s = wv*5 + i, i<5. s<8: Wu, s<16: Wg, s<20: X.
#define UG_STAGE(tc, bf) do { \
        const int kc0_ = (tc) * 64; \
        _Pragma("unroll") \
        for (int i = 0; i < 5; i++) { \
            int s = wv * 5 + i; \
            if (s < 16) { \
                int p = (s & 7) * 64 + lane; \
                int row = p >> 4, ul = p & 15; \
                int col = ((ul ^ (row & 7)) << 2); \
                const float* src = (s < 8 ? ub : gb) + (size_t)row * C_DIM + kc0_ + col; \
                gload16(src, (void*)&(s < 8 ? WuS : WgS)[bf][(s & 7) * 64]); \
            } else { \
                int q = (s - 16) * 64 + lane; \
                int row = q >> 3, xl = q & 7; \
                int col = ((xl ^ (row & 7)) << 3); \
                int tok = toks_s[row]; if (tok < 0) tok = 0; \
                const ushort* src = xbf + (size_t)tok * C_DIM + kc0_ + col; \
                gload16(src, (void*)&XS[bf][(s - 16) * 512]); \
            } \
        } \
    } while (0)

    const int lc = lane & 15, kg = lane >> 4;
    const int mf = wv >> 1, nf = wv & 1;
    const int rm = mf * 16 + lc, sm = rm & 7;
    const int rn = nf * 16 + lc, sn = rn & 7;
    f32x4 au = {0,0,0,0}, ag = {0,0,0,0};

    UG_STAGE(0, 0);
    UG_STAGE(1, 1);

#pragma unroll 1
    for (int t = 0; t < 16; t++) {
        const int b = t & 1;
        __syncthreads();   // chunk t landed (compiler drains vmcnt), all waves aligned
#pragma unroll
        for (int k32 = 0; k32 < 2; k32++) {
            int xunit = rm * 8 + ((k32 * 4 + kg) ^ sm);
            short8 a = *reinterpret_cast<const short8*>(&XS[b][xunit * 8]);
            int ks = k32 * 8 + kg * 2;
            float4 w0 = WuS[b][rn * 16 + (ks ^ sn)];
            float4 w1 = WuS[b][rn * 16 + ((ks + 1) ^ sn)];
            au = MFMA(a, pack8(w0, w1), au);
            float4 g0 = WgS[b][rn * 16 + (ks ^ sn)];
            float4 g1 = WgS[b][rn * 16 + ((ks + 1) ^ sn)];
            ag = MFMA(a, pack8(g0, g1), ag);
        }
        __syncthreads();   // all waves done reading buf b
        if (t + 2 < 16) UG_STAGE(t + 2, b);
    }
#undef UG_STAGE

    ushort* __restrict__ outp = sh ? hsbuf : hbuf;
    const int hcol = n0 + nf * 16 + lc;
#pragma unroll
    for (int j = 0; j < 4; j++) {
        int m = mf * 16 + kg * 4 + j;
        int tok = toks_s[m];
        if (tok >= 0) {
            float g = ag[j], u = au[j];
            float hv = u * (g / (1.f + __expf(-g)));
            outp[(size_t)tok * H_DIM + hcol] = f2bf(hv);
        }
    }
}

// down: BM=32 tokens x BN=32 c-rows, K=2048 in 32 chunks of 64.
// grid (9 [8=shared], C/32=32, 8 token-tiles).
__global__ __launch_bounds__(256) void down_mfma(
    const float* __restrict__ dwn, const float* __restrict__ w_down_s,
    const ushort* __restrict__ hbuf, const ushort* __restrict__ hsbuf,
    const int* __restrict__ cnt, const int* __restrict__ list,
    float* __restrict__ y, float* __restrict__ yspart)
{
    const int e = blockIdx.x, by = blockIdx.y, tt = blockIdx.z;
    const bool sh = (e == E_NUM);
    const int n = sh ? T_TOK : cnt[e];
    if (tt * 32 >= n) return;
    const int tid = threadIdx.x, lane = tid & 63, wv = tid >> 6;

    __shared__ float4 WdS[2][512];
    __shared__ ushort HxS[2][2048];
    __shared__ int toks_s[32];
    if (tid < 32) {
        int t = tt * 32 + tid;
        toks_s[tid] = (t < n) ? (sh ? t : list[e * T_TOK + t]) : -1;
    }
    __syncthreads();

    const int n0 = by * 32;
    const float* __restrict__ db = (sh ? w_down_s : dwn + (size_t)e * C_DIM * H_DIM) + (size_t)n0 * H_DIM;
    const ushort* __restrict__ hin = sh ? hsbuf : hbuf;

    // slots s = wv*3 + i, i<3. s<8: Wd, s<12: Hx.
#define DN_STAGE(tc, bf) do { \
        const int kc0_ = (tc) * 64; \
        _Pragma("unroll") \
        for (int i = 0; i < 3; i++) { \
            int s = wv * 3 + i; \
            if (s < 8) { \
                int p = s * 64 + lane; \
                int row = p >> 4, ul = p & 15; \
                int col = ((ul ^ (row & 7)) << 2); \
                const float* src = db + (size_t)row * H_DIM + kc0_ + col; \
                gload16(src, (void*)&WdS[bf][s * 64]); \
            } else { \
                int q = (s - 8) * 64 + lane; \
                int row = q >> 3, xl = q & 7; \
                int col = ((xl ^ (row & 7)) << 3); \
                int tok = toks_s[row]; if (tok < 0) tok = 0; \
                const ushort* src = hin + (size_t)tok * H_DIM + kc0_ + col; \
                gload16(src, (void*)&HxS[bf][(s - 8) * 512]); \
            } \
        } \
    } while (0)

    const int lc = lane & 15, kg = lane >> 4;
    const int mf = wv >> 1, nf = wv & 1;
    const int rm = mf * 16 + lc, sm = rm & 7;
    const int rn = nf * 16 + lc, sn = rn & 7;
    f32x4 acc = {0,0,0,0};

    DN_STAGE(0, 0);
    DN_STAGE(1, 1);

#pragma unroll 1
    for (int t = 0; t < 32; t++) {
        const int b = t & 1;
        __syncthreads();
#pragma unroll
        for (int k32 = 0; k32 < 2; k32++) {
            int xunit = rm * 8 + ((k32 * 4 + kg) ^ sm);
            short8 a = *reinterpret_cast<const short8*>(&HxS[b][xunit * 8]);
            int ks = k32 * 8 + kg * 2;
            float4 w0 = WdS[b][rn * 16 + (ks ^ sn)];
            float4 w1 = WdS[b][rn * 16 + ((ks + 1) ^ sn)];
            acc = MFMA(a, pack8(w0, w1), acc);
        }
        __syncthreads();
        if (t + 2 < 32) DN_STAGE(t + 2, b);
    }
#undef DN_STAGE

    float* __restrict__ outp = sh ? yspart : y;
    const int cglob = n0 + nf * 16 + lc;
#pragma unroll
    for (int j = 0; j < 4; j++) {
        int m = mf * 16 + kg * 4 + j;
        int tok = toks_s[m];
        if (tok >= 0) outp[(size_t)tok * C_DIM + cglob] = acc[j];
    }
}

__global__ __launch_bounds__(256) void add_kernel(float* __restrict__ y, const float* __restrict__ ys)
{
    int i = blockIdx.x * 256 + threadIdx.x;
    float4 a = reinterpret_cast<float4*>(y)[i];
    float4 b = reinterpret_cast<const float4*>(ys)[i];
    a.x += b.x; a.y += b.y; a.z += b.z; a.w += b.w;
    reinterpret_cast<float4*>(y)[i] = a;
}

extern "C" void kernel_launch(void* const* d_in, const int* in_sizes, int n_in,
                              void* d_out, int out_size, void* d_ws, size_t ws_size,
                              hipStream_t stream)
{
    const float* x        = (const float*)d_in[0];
    const float* up       = (const float*)d_in[1];
    const float* gate     = (const float*)d_in[2];
    const float* dwn      = (const float*)d_in[3];
    const float* router   = (const float*)d_in[4];
    const float* w_up_s   = (const float*)d_in[5];
    const float* w_gate_s = (const float*)d_in[6];
    const float* w_down_s = (const float*)d_in[7];

    char* ws = (char*)d_ws;
    int* cnt      = (int*)(ws + WS_CNT);
    int* list     = (int*)(ws + WS_LIST);
    ushort* xbf   = (ushort*)(ws + WS_XBF);
    ushort* hbuf  = (ushort*)(ws + WS_HBUF);
    ushort* hsbuf = (ushort*)(ws + WS_HSBUF);
    float* yspart = (float*)(ws + WS_YS);
    float* y = (float*)d_out;

    hipMemsetAsync(cnt, 0, E_NUM * sizeof(int), stream);
    router_kernel<<<T_TOK, 256, 0, stream>>>(x, router, cnt, list, xbf);
    ug_mfma<<<dim3(E_NUM + 1, H_DIM / 32, 8), 256, 0, stream>>>(
        xbf, up, gate, w_up_s, w_gate_s, cnt, list, hbuf, hsbuf);
    down_mfma<<<dim3(E_NUM + 1, C_DIM / 32, 8), 256, 0, stream>>>(
        dwn, w_down_s, hbuf, hsbuf, cnt, list, y, yspart);
    add_kernel<<<(T_TOK * C_DIM / 4) / 256, 256, 0, stream>>>(y, yspart);
}